// Round 3
// baseline (474.492 us; speedup 1.0000x reference)
//
#include <hip/hip_runtime.h>

#define BTOT 1048576
#define D 17
#define H 8
#define OUT 6
#define E 4
#define G1 64
#define G2 32

typedef float v2fa __attribute__((ext_vector_type(2), aligned(8)));
typedef float v4fa __attribute__((ext_vector_type(4), aligned(16)));
typedef float v4fu __attribute__((ext_vector_type(4), aligned(4)));

__global__ __launch_bounds__(256) void hybrid_ruc_kernel(
    const float* __restrict__ x,
    const float* __restrict__ eW1, const float* __restrict__ eb1,
    const float* __restrict__ eW2, const float* __restrict__ eb2,
    const float* __restrict__ eW3, const float* __restrict__ eb3,
    const float* __restrict__ gW1, const float* __restrict__ gb1,
    const float* __restrict__ gW2, const float* __restrict__ gb2,
    const float* __restrict__ gW3, const float* __restrict__ gb3,
    float* __restrict__ out)
{
    const long long b = (long long)blockIdx.x * 256 + threadIdx.x;

    // ---- x row: 4x dwordx4 + 1 dword (dword-aligned unaligned-vector loads) ----
    const float* xrow = x + b * D;
    v4fu xq0 = *(const v4fu*)(xrow);
    v4fu xq1 = *(const v4fu*)(xrow + 4);
    v4fu xq2 = *(const v4fu*)(xrow + 8);
    v4fu xq3 = *(const v4fu*)(xrow + 12);
    float xr[D];
    xr[0] = xq0.x;  xr[1] = xq0.y;  xr[2] = xq0.z;  xr[3] = xq0.w;
    xr[4] = xq1.x;  xr[5] = xq1.y;  xr[6] = xq1.z;  xr[7] = xq1.w;
    xr[8] = xq2.x;  xr[9] = xq2.y;  xr[10] = xq2.z; xr[11] = xq2.w;
    xr[12] = xq3.x; xr[13] = xq3.y; xr[14] = xq3.z; xr[15] = xq3.w;
    xr[16] = xrow[16];

    // ---- gating layer1 (17->64) fused with layer2 (64->32) ----
    // 8 fully-unrolled tiles of 8 h1 units: straight-line code so the
    // scheduler can hoist s_load batches across tile boundaries.
    // Accumulation order identical to rounds 1-2 (bias first, ascending i/c).
    float h2[G2];
    #pragma unroll
    for (int j = 0; j < G2; ++j) h2[j] = gb2[j];

    #pragma unroll
    for (int jt = 0; jt < G1 / 8; ++jt) {
        float h1t[8];
        #pragma unroll
        for (int c = 0; c < 8; ++c) h1t[c] = gb1[jt * 8 + c];
        #pragma unroll
        for (int i = 0; i < D; ++i) {
            const float xi = xr[i];
            const float* wr = gW1 + i * G1 + jt * 8;   // uniform addr -> s_load
            #pragma unroll
            for (int c = 0; c < 8; ++c)
                h1t[c] = __builtin_fmaf(xi, wr[c], h1t[c]);
        }
        #pragma unroll
        for (int c = 0; c < 8; ++c) {
            const float hv = fmaxf(h1t[c], 0.0f);
            const float* wr = gW2 + (jt * 8 + c) * G2; // uniform addr
            #pragma unroll
            for (int j = 0; j < G2; ++j)
                h2[j] = __builtin_fmaf(hv, wr[j], h2[j]);
        }
    }

    // ---- gating layer3 (32->4), j ascending ----
    float lg[E];
    #pragma unroll
    for (int e = 0; e < E; ++e) lg[e] = gb3[e];
    #pragma unroll
    for (int j = 0; j < G2; ++j) {
        const float hv = fmaxf(h2[j], 0.0f);
        #pragma unroll
        for (int e = 0; e < E; ++e)
            lg[e] = __builtin_fmaf(hv, gW3[j * E + e], lg[e]);
    }

    // ---- argmax, first-max-wins (matches jnp.argmax) ----
    int sel = 0;
    float best = lg[0];
    #pragma unroll
    for (int e = 1; e < E; ++e) {
        if (lg[e] > best) { best = lg[e]; sel = e; }
    }

    // ---- experts: all 4, fully unrolled, uniform SGPR weights ----
    float pred[OUT];
    #pragma unroll
    for (int o = 0; o < OUT; ++o) pred[o] = 0.0f;

    #pragma unroll
    for (int e = 0; e < E; ++e) {
        // layer1: 17 -> 8
        float t1[H];
        #pragma unroll
        for (int h = 0; h < H; ++h) t1[h] = eb1[e * H + h];
        #pragma unroll
        for (int i = 0; i < D; ++i) {
            const float xi = xr[i];
            const float* wr = eW1 + e * D * H + i * H;
            #pragma unroll
            for (int h = 0; h < H; ++h)
                t1[h] = __builtin_fmaf(xi, wr[h], t1[h]);
        }
        // layer2: 8 -> 8
        float t2[H];
        #pragma unroll
        for (int h = 0; h < H; ++h) t2[h] = eb2[e * H + h];
        #pragma unroll
        for (int k = 0; k < H; ++k) {
            const float tv = fmaxf(t1[k], 0.0f);
            const float* wr = eW2 + e * H * H + k * H;
            #pragma unroll
            for (int h = 0; h < H; ++h)
                t2[h] = __builtin_fmaf(tv, wr[h], t2[h]);
        }
        // layer3: 8 -> 6
        float po[OUT];
        #pragma unroll
        for (int o = 0; o < OUT; ++o) po[o] = eb3[e * OUT + o];
        #pragma unroll
        for (int k = 0; k < H; ++k) {
            const float tv = fmaxf(t2[k], 0.0f);
            const float* wr = eW3 + e * H * OUT + k * OUT;
            #pragma unroll
            for (int o = 0; o < OUT; ++o)
                po[o] = __builtin_fmaf(tv, wr[o], po[o]);
        }
        #pragma unroll
        for (int o = 0; o < OUT; ++o)
            pred[o] = (sel == e) ? po[o] : pred[o];  // exactly one e matches
    }

    // ---- stores: predictions [B,6] (8B-aligned) then logits [B,4] (16B) ----
    float* po = out + b * OUT;
    *(v2fa*)(po)     = (v2fa){pred[0], pred[1]};
    *(v2fa*)(po + 2) = (v2fa){pred[2], pred[3]};
    *(v2fa*)(po + 4) = (v2fa){pred[4], pred[5]};
    float* lo = out + (long long)BTOT * OUT + b * E;
    *(v4fa*)(lo) = (v4fa){lg[0], lg[1], lg[2], lg[3]};
}

extern "C" void kernel_launch(void* const* d_in, const int* in_sizes, int n_in,
                              void* d_out, int out_size, void* d_ws, size_t ws_size,
                              hipStream_t stream) {
    const float* x   = (const float*)d_in[0];
    const float* eW1 = (const float*)d_in[1];
    const float* eb1 = (const float*)d_in[2];
    const float* eW2 = (const float*)d_in[3];
    const float* eb2 = (const float*)d_in[4];
    const float* eW3 = (const float*)d_in[5];
    const float* eb3 = (const float*)d_in[6];
    const float* gW1 = (const float*)d_in[7];
    const float* gb1 = (const float*)d_in[8];
    const float* gW2 = (const float*)d_in[9];
    const float* gb2 = (const float*)d_in[10];
    const float* gW3 = (const float*)d_in[11];
    const float* gb3 = (const float*)d_in[12];
    float* out = (float*)d_out;

    dim3 grid(BTOT / 256), block(256);
    hipLaunchKernelGGL(hybrid_ruc_kernel, grid, block, 0, stream,
                       x, eW1, eb1, eW2, eb2, eW3, eb3,
                       gW1, gb1, gW2, gb2, gW3, gb3, out);
}

// Round 5
// 220.184 us; speedup vs baseline: 2.1550x; 2.1550x over previous
//
#include <hip/hip_runtime.h>

#define BTOT 1048576
#define D 17
#define H 8
#define OUT 6
#define E 4
#define G1 64
#define G2 32

typedef short bf8 __attribute__((ext_vector_type(8)));          // 8 bf16 (4 VGPR)
typedef float f4 __attribute__((ext_vector_type(4), aligned(16)));
typedef float f4u __attribute__((ext_vector_type(4), aligned(4)));
typedef float f2u __attribute__((ext_vector_type(2), aligned(4)));
typedef unsigned int u4 __attribute__((ext_vector_type(4)));

#define MFMA16 __builtin_amdgcn_mfma_f32_16x16x32_bf16

__device__ __forceinline__ unsigned int fbits(float x){ union{float f; unsigned int u;} a; a.f = x; return a.u; }
__device__ __forceinline__ float bitsf(unsigned int u){ union{unsigned int u; float f;} a; a.u = u; return a.f; }
__device__ __forceinline__ unsigned short bf_rne(float x){ unsigned int u = fbits(x); u += 0x7FFFu + ((u>>16)&1u); return (unsigned short)(u>>16); }

// 3-way split of an fp32 pair into packed bf16 levels: trunc / trunc / RNE.
// q1/q2/q3 hold {lo=a, hi=b} bf16 pairs for levels 1..3.
__device__ __forceinline__ void split2(float a, float b,
                                       unsigned int& q1, unsigned int& q2, unsigned int& q3){
    unsigned int ua = fbits(a), ub = fbits(b);
    unsigned int a1 = ua & 0xFFFF0000u, b1 = ub & 0xFFFF0000u;
    float ra = a - bitsf(a1), rb = b - bitsf(b1);
    unsigned int a2 = fbits(ra) & 0xFFFF0000u, b2 = fbits(rb) & 0xFFFF0000u;
    float ra2 = ra - bitsf(a2), rb2 = rb - bitsf(b2);
    unsigned int a3 = fbits(ra2); a3 += 0x7FFFu + ((a3>>16)&1u);
    unsigned int b3 = fbits(rb2); b3 += 0x7FFFu + ((b3>>16)&1u);
    q1 = b1 | (a1 >> 16);
    q2 = b2 | (a2 >> 16);
    q3 = (b3 & 0xFFFF0000u) | (a3 >> 16);
}

__device__ __forceinline__ void split8(f4 lo, f4 hi, bf8& A1, bf8& A2, bf8& A3){
    unsigned int p1[4], p2[4], p3[4];
    split2(lo.x, lo.y, p1[0], p2[0], p3[0]);
    split2(lo.z, lo.w, p1[1], p2[1], p3[1]);
    split2(hi.x, hi.y, p1[2], p2[2], p3[2]);
    split2(hi.z, hi.w, p1[3], p2[3], p3[3]);
    union { u4 u; bf8 s; } r1, r2, r3;
    r1.u = (u4){p1[0], p1[1], p1[2], p1[3]};
    r2.u = (u4){p2[0], p2[1], p2[2], p2[3]};
    r3.u = (u4){p3[0], p3[1], p3[2], p3[3]};
    A1 = r1.s; A2 = r2.s; A3 = r3.s;
}

__device__ __forceinline__ unsigned short split_level(float w, int l){
    unsigned int u1 = fbits(w) & 0xFFFF0000u;
    if (l == 0) return (unsigned short)(u1 >> 16);
    float r = w - bitsf(u1);
    unsigned int u2 = fbits(r) & 0xFFFF0000u;
    if (l == 1) return (unsigned short)(u2 >> 16);
    float r2 = r - bitsf(u2);
    return bf_rne(r2);
}

// ---- Pre-kernel: build MFMA B-operand layouts in workspace (bf16, [n][k] k-contig) ----
// ws ushort offsets: B1L 0 (3*64*32) | B2L 6144 (3*32*64) | Be1 12288 (32*32)
//                    Be2 13312 (32*32, block-diag) | Be3 14336 (16*32, expert-stacked)
__global__ void hybrid_pre(const float* __restrict__ eW1, const float* __restrict__ eW2,
                           const float* __restrict__ eW3, const float* __restrict__ gW1,
                           const float* __restrict__ gW2, unsigned short* __restrict__ wsB)
{
    const int t = threadIdx.x;
    for (int i = t; i < 3*64*32; i += 256) {                 // B1L[l][n][k]
        int k = i & 31, n = (i >> 5) & 63, l = i >> 11;
        float w = (k < D) ? gW1[k*G1 + n] : 0.f;
        wsB[i] = split_level(w, l);
    }
    for (int i = t; i < 3*32*64; i += 256) {                 // B2L[l][n][k]
        int k = i & 63, n = (i >> 6) & 31, l = i >> 11;
        float w = gW2[k*G2 + n];
        wsB[6144 + i] = split_level(w, l);
    }
    for (int i = t; i < 1024; i += 256) {                    // Be1[n][k]: n={e,h}, k=i
        int k = i & 31, n = i >> 5, e = n >> 3, h = n & 7;
        float w = (k < D) ? eW1[(e*D + k)*H + h] : 0.f;
        wsB[12288 + i] = bf_rne(w);
    }
    for (int i = t; i < 1024; i += 256) {                    // Be2[n][k] block-diag
        int k = i & 31, n = i >> 5, e = n >> 3, j = n & 7, kk = k - e*8;
        float w = (kk >= 0 && kk < 8) ? eW2[(e*H + kk)*H + j] : 0.f;
        wsB[13312 + i] = bf_rne(w);
    }
    for (int i = t; i < 512; i += 256) {                     // Be3[n][k] stacked by expert
        int k = i & 31, n = i >> 5, e = k >> 3, kk = k & 7;
        float w = (n < OUT) ? eW3[(e*H + kk)*OUT + n] : 0.f;
        wsB[14336 + i] = bf_rne(w);
    }
}

// ---- Main kernel: 256 threads = 4 waves; each wave owns 64 samples, private LDS slice,
// ---- NO __syncthreads (within-wave LDS ops are in-order). ----
__global__ __launch_bounds__(256, 2) void hybrid_main(
    const float* __restrict__ x,
    const float* __restrict__ eb1, const float* __restrict__ eb2, const float* __restrict__ eb3,
    const float* __restrict__ gb1, const float* __restrict__ gb2,
    const float* __restrict__ gW3, const float* __restrict__ gb3,
    const unsigned short* __restrict__ wsB,
    float* __restrict__ out)
{
    __shared__ char lds_all[4 * 16384];
    const int tid = threadIdx.x;
    const int wave = tid >> 6, lane = tid & 63;
    const int q = lane >> 4, c = lane & 15;
    char* slice = lds_all + wave * 16384;
    // Aliased per-wave regions (phase-ordered; safe via in-order DS pipe + wave_barrier):
    float* sx   = (float*)slice;                           // [64][36] f32   (phase X->L1)
    float* sh1  = (float*)slice;                           // [64][64] f32, k-block swizzled (L1->L2)
    float* sh2  = (float*)slice;                           // [64][36] f32   (L2->L3)
    unsigned short* sAe2 = (unsigned short*)slice;         // [64][40] bf16  (eL1->eL2)
    unsigned short* sAe3 = (unsigned short*)(slice + 5120);// [64][40] bf16  (eL2->eL3)
    float* spred = (float*)(slice + 10240);                // [64][8]  f32   (eL3->store)
    int*   ssel  = (int*)(slice + 12288);                  // [64]

    const long long samp0 = (long long)blockIdx.x * 256 + wave * 64;

    // ---- Phase X: stage this lane's x row into sx (zero-padded k=17..31) ----
    {
        const float* xr = x + (samp0 + lane) * D;
        f4u x0 = *(const f4u*)xr, x1 = *(const f4u*)(xr+4);
        f4u x2 = *(const f4u*)(xr+8), x3 = *(const f4u*)(xr+12);
        float x16 = xr[16];
        float* dst = sx + lane * 36;
        *(f4*)(dst)      = (f4){x0.x,x0.y,x0.z,x0.w};
        *(f4*)(dst + 4)  = (f4){x1.x,x1.y,x1.z,x1.w};
        *(f4*)(dst + 8)  = (f4){x2.x,x2.y,x2.z,x2.w};
        *(f4*)(dst + 12) = (f4){x3.x,x3.y,x3.z,x3.w};
        *(f4*)(dst + 16) = (f4){x16, 0.f, 0.f, 0.f};
        *(f4*)(dst + 20) = (f4){0.f,0.f,0.f,0.f};
        *(f4*)(dst + 24) = (f4){0.f,0.f,0.f,0.f};
        *(f4*)(dst + 28) = (f4){0.f,0.f,0.f,0.f};
    }
    __builtin_amdgcn_wave_barrier();

    // ---- Preload gating B-frags + biases ----
    bf8 B1f[4][3];
    #pragma unroll
    for (int nt = 0; nt < 4; ++nt)
        #pragma unroll
        for (int l = 0; l < 3; ++l)
            B1f[nt][l] = *(const bf8*)(wsB + ((l*64 + nt*16 + c)*32 + q*8));
    float bias1[4];
    #pragma unroll
    for (int nt = 0; nt < 4; ++nt) bias1[nt] = gb1[nt*16 + c];

    // ---- L1: hoist ALL A reads+splits (sx fully consumed before sh1 overwrites it) ----
    bf8 A1[4], A2[4], A3[4];
    #pragma unroll
    for (int mt = 0; mt < 4; ++mt) {
        const float* src = sx + (mt*16 + c)*36 + q*8;
        f4 lo = *(const f4*)src, hi = *(const f4*)(src + 4);
        split8(lo, hi, A1[mt], A2[mt], A3[mt]);
    }
    __builtin_amdgcn_wave_barrier();

    // ---- L1 MFMA (7-product split) + epilogue -> sh1 (swizzled) ----
    #pragma unroll
    for (int mt = 0; mt < 4; ++mt) {
        #pragma unroll
        for (int nt = 0; nt < 4; ++nt) {
            f4 am = {0.f,0.f,0.f,0.f}, ac = {0.f,0.f,0.f,0.f};
            am = MFMA16(A1[mt], B1f[nt][0], am, 0,0,0);
            ac = MFMA16(A1[mt], B1f[nt][1], ac, 0,0,0);
            ac = MFMA16(A2[mt], B1f[nt][0], ac, 0,0,0);
            ac = MFMA16(A1[mt], B1f[nt][2], ac, 0,0,0);
            ac = MFMA16(A2[mt], B1f[nt][1], ac, 0,0,0);
            ac = MFMA16(A3[mt], B1f[nt][0], ac, 0,0,0);
            ac = MFMA16(A3[mt], B1f[nt][1], ac, 0,0,0);
            #pragma unroll
            for (int r = 0; r < 4; ++r) {
                float h = fmaxf(am[r] + ac[r] + bias1[nt], 0.f);
                int row = mt*16 + q*4 + r;
                int blk = (nt*2 + (c>>3)) ^ (row & 7);      // bank swizzle
                sh1[row*64 + blk*8 + (c&7)] = h;
            }
        }
    }
    __builtin_amdgcn_wave_barrier();

    // ---- L2: B-frags + per-mt A-split from sh1 -> sh2 ----
    bf8 B2f[2][2][3];
    #pragma unroll
    for (int nt = 0; nt < 2; ++nt)
        #pragma unroll
        for (int ks = 0; ks < 2; ++ks)
            #pragma unroll
            for (int l = 0; l < 3; ++l)
                B2f[nt][ks][l] = *(const bf8*)(wsB + 6144 + ((l*32 + nt*16 + c)*64 + ks*32 + q*8));
    float bias2[2];
    #pragma unroll
    for (int nt = 0; nt < 2; ++nt) bias2[nt] = gb2[nt*16 + c];

    #pragma unroll
    for (int mt = 0; mt < 4; ++mt) {
        bf8 C1[2], C2[2], C3[2];
        #pragma unroll
        for (int ks = 0; ks < 2; ++ks) {
            int row = mt*16 + c;
            int blk = (ks*4 + q) ^ (row & 7);
            const float* src = sh1 + row*64 + blk*8;
            f4 lo = *(const f4*)src, hi = *(const f4*)(src + 4);
            split8(lo, hi, C1[ks], C2[ks], C3[ks]);
        }
        #pragma unroll
        for (int nt = 0; nt < 2; ++nt) {
            f4 am = {0.f,0.f,0.f,0.f}, ac = {0.f,0.f,0.f,0.f};
            #pragma unroll
            for (int ks = 0; ks < 2; ++ks) {
                am = MFMA16(C1[ks], B2f[nt][ks][0], am, 0,0,0);
                ac = MFMA16(C1[ks], B2f[nt][ks][1], ac, 0,0,0);
                ac = MFMA16(C2[ks], B2f[nt][ks][0], ac, 0,0,0);
                ac = MFMA16(C1[ks], B2f[nt][ks][2], ac, 0,0,0);
                ac = MFMA16(C2[ks], B2f[nt][ks][1], ac, 0,0,0);
                ac = MFMA16(C3[ks], B2f[nt][ks][0], ac, 0,0,0);
                ac = MFMA16(C3[ks], B2f[nt][ks][1], ac, 0,0,0);
            }
            #pragma unroll
            for (int r = 0; r < 4; ++r) {
                float h = fmaxf(am[r] + ac[r] + bias2[nt], 0.f);   // post-relu h2
                int row = mt*16 + q*4 + r;
                sh2[row*36 + nt*16 + c] = h;
            }
        }
    }
    __builtin_amdgcn_wave_barrier();

    // ---- L3 (per-thread fp32 VALU): logits, argmax, store logits ----
    {
        const float* hr = sh2 + lane*36;
        f4 hv[8];
        #pragma unroll
        for (int i = 0; i < 8; ++i) hv[i] = *(const f4*)(hr + i*4);
        float lg[E];
        #pragma unroll
        for (int e = 0; e < E; ++e) lg[e] = gb3[e];
        #pragma unroll
        for (int k = 0; k < G2; ++k) {
            float h = hv[k>>2][k&3];
            #pragma unroll
            for (int e = 0; e < E; ++e)
                lg[e] = __builtin_fmaf(h, gW3[k*E + e], lg[e]);
        }
        int sel = 0; float best = lg[0];
        #pragma unroll
        for (int e = 1; e < E; ++e) if (lg[e] > best) { best = lg[e]; sel = e; }
        ssel[lane] = sel;
        float* lo = out + (long long)BTOT * OUT + (samp0 + lane) * E;
        *(f4*)lo = (f4){lg[0], lg[1], lg[2], lg[3]};
    }
    __builtin_amdgcn_wave_barrier();

    // ---- Experts (plain bf16 MFMA; mask at t2; stacked W3 emits selected expert) ----
    bf8 Be1f[2], Be2f[2], Be3f;
    #pragma unroll
    for (int nt = 0; nt < 2; ++nt) {
        Be1f[nt] = *(const bf8*)(wsB + 12288 + (nt*16 + c)*32 + q*8);
        Be2f[nt] = *(const bf8*)(wsB + 13312 + (nt*16 + c)*32 + q*8);
    }
    Be3f = *(const bf8*)(wsB + 14336 + c*32 + q*8);
    float be1v[2], be2v[2];
    #pragma unroll
    for (int nt = 0; nt < 2; ++nt) { be1v[nt] = eb1[nt*16 + c]; be2v[nt] = eb2[nt*16 + c]; }

    #pragma unroll
    for (int mt = 0; mt < 4; ++mt) {                       // eL1: x1 (lvl-1 frags) -> t1
        #pragma unroll
        for (int nt = 0; nt < 2; ++nt) {
            f4 acc = {0.f,0.f,0.f,0.f};
            acc = MFMA16(A1[mt], Be1f[nt], acc, 0,0,0);
            #pragma unroll
            for (int r = 0; r < 4; ++r) {
                float t = fmaxf(acc[r] + be1v[nt], 0.f);
                int row = mt*16 + q*4 + r;
                sAe2[row*40 + nt*16 + c] = (unsigned short)(fbits(t) >> 16);
            }
        }
    }
    __builtin_amdgcn_wave_barrier();

    #pragma unroll
    for (int mt = 0; mt < 4; ++mt) {                       // eL2 (block-diag) -> masked t2
        bf8 Af = *(const bf8*)(sAe2 + (mt*16 + c)*40 + q*8);
        f4 acc[2];
        #pragma unroll
        for (int nt = 0; nt < 2; ++nt) {
            acc[nt] = (f4){0.f,0.f,0.f,0.f};
            acc[nt] = MFMA16(Af, Be2f[nt], acc[nt], 0,0,0);
        }
        #pragma unroll
        for (int r = 0; r < 4; ++r) {
            int row = mt*16 + q*4 + r;
            int se = ssel[row];
            #pragma unroll
            for (int nt = 0; nt < 2; ++nt) {
                int ecol = nt*2 + (c>>3);
                float t = (se == ecol) ? fmaxf(acc[nt][r] + be2v[nt], 0.f) : 0.f;
                sAe3[row*40 + nt*16 + c] = (unsigned short)(fbits(t) >> 16);
            }
        }
    }
    __builtin_amdgcn_wave_barrier();

    #pragma unroll
    for (int mt = 0; mt < 4; ++mt) {                       // eL3 (stacked) -> selected pred
        bf8 Af = *(const bf8*)(sAe3 + (mt*16 + c)*40 + q*8);
        f4 acc = {0.f,0.f,0.f,0.f};
        acc = MFMA16(Af, Be3f, acc, 0,0,0);
        #pragma unroll
        for (int r = 0; r < 4; ++r) {
            int row = mt*16 + q*4 + r;
            int se = ssel[row];
            if (c < OUT) spred[row*8 + c] = acc[r] + eb3[se*OUT + c];
        }
    }
    __builtin_amdgcn_wave_barrier();

    // ---- pred store (thread-major, vectorized) ----
    {
        const float* pr = spred + lane*8;
        f4 p0 = *(const f4*)pr;
        float p4 = pr[4], p5 = pr[5];
        float* po = out + (samp0 + lane) * OUT;
        *(f4u*)po = p0;
        *(f2u*)(po + 4) = (f2u){p4, p5};
    }
}

extern "C" void kernel_launch(void* const* d_in, const int* in_sizes, int n_in,
                              void* d_out, int out_size, void* d_ws, size_t ws_size,
                              hipStream_t stream) {
    const float* x   = (const float*)d_in[0];
    const float* eW1 = (const float*)d_in[1];
    const float* eb1 = (const float*)d_in[2];
    const float* eW2 = (const float*)d_in[3];
    const float* eb2 = (const float*)d_in[4];
    const float* eW3 = (const float*)d_in[5];
    const float* eb3 = (const float*)d_in[6];
    const float* gW1 = (const float*)d_in[7];
    const float* gb1 = (const float*)d_in[8];
    const float* gW2 = (const float*)d_in[9];
    const float* gb2 = (const float*)d_in[10];
    const float* gW3 = (const float*)d_in[11];
    const float* gb3 = (const float*)d_in[12];
    float* out = (float*)d_out;
    unsigned short* wsB = (unsigned short*)d_ws;

    hipLaunchKernelGGL(hybrid_pre, dim3(1), dim3(256), 0, stream,
                       eW1, eW2, eW3, gW1, gW2, wsB);
    hipLaunchKernelGGL(hybrid_main, dim3(BTOT / 256), dim3(256), 0, stream,
                       x, eb1, eb2, eb3, gb1, gb2, gW3, gb3, wsB, out);
}